// Round 1
// baseline (129.970 us; speedup 1.0000x reference)
//
#include <hip/hip_runtime.h>
#include <math.h>

#define BATCH 8192
#define BLK 256
#define NSPLIT 32
#define CHUNK (BATCH / NSPLIT)  // 256 keys per split == BLK

// ---------------------------------------------------------------------------
// Branch-free fast tanh: tanh(x) = 1 - 2/(e^{2x}+1).
// v_exp + v_rcp (~1 ulp each) -> abs err ~2e-7; saturates exactly to +-1 at
// +-inf (e=inf -> rcp=0 -> 1 ; e=0 -> 1-2 = -1). Replaces ~60-100-instr
// branchy libm tanhf whose 60x inlining made mlp_kernel I-fetch/latency bound
// (40 us at 0.7% VALUBusy).
__device__ __forceinline__ float tanh_fast(float x) {
  float e = __expf(x + x);
  return fmaf(-2.0f, __builtin_amdgcn_rcpf(e + 1.0f), 1.0f);
}

// Two-row interleaved Linear+tanh: every weight load (wave-uniform address ->
// compiler emits s_load on the scalar pipe, zero VALU/LDS cost) feeds 2 FMAs,
// and the two independent rows give 2x ILP on the dependent tanh chains.
// All loops fully unrolled -> arrays stay in registers (no scratch).
template <int IN, int OUT>
__device__ __forceinline__ void layer2_tanh(
    const float* x0, const float* x1, float* y0, float* y1,
    const float* __restrict__ W, const float* __restrict__ bias) {
  float acc0[OUT], acc1[OUT];
#pragma unroll
  for (int o = 0; o < OUT; o++) {
    float b = bias[o];
    acc0[o] = b;
    acc1[o] = b;
  }
#pragma unroll
  for (int i = 0; i < IN; i++) {
    float a0 = x0[i], a1 = x1[i];
#pragma unroll
    for (int o = 0; o < OUT; o++) {
      float w = W[i * OUT + o];  // uniform -> s_load, scalar cache resident
      acc0[o] = fmaf(a0, w, acc0[o]);
      acc1[o] = fmaf(a1, w, acc1[o]);
    }
  }
#pragma unroll
  for (int o = 0; o < OUT; o++) {
    y0[o] = tanh_fast(acc0[o]);
    y1[o] = tanh_fast(acc1[o]);
  }
}

__device__ __forceinline__ float dot4(float4 a, float4 b) {
  return fmaf(a.x, b.x, fmaf(a.y, b.y, fmaf(a.z, b.z, a.w * b.w)));
}

// Fused MLP + split attention. Block (qb, sp) computes the MLP for its 256
// query rows AND its 256 key rows (2 evals/thread, interleaved), stages the
// split's K/V in LDS, then runs the no-max single-pass attention over the
// chunk. 64x redundant MLP compute, but it's only ~40% of the attention
// loop's issue cost and now runs at ~16 waves/CU instead of 1 wave/SIMD.
// |s| <= ||q||*||k||/2 << 88 so exp cannot overflow and the max-rescale
// cancels exactly in o/l (same argument as the previous verified kernel).
__global__ __launch_bounds__(BLK, 3) void fused_attn(
    const float* __restrict__ in,
    const float* __restrict__ W_fm, const float* __restrict__ b_fm,
    const float* __restrict__ W_c1, const float* __restrict__ b_c1,
    const float* __restrict__ W_p1, const float* __restrict__ b_p1,
    const float* __restrict__ W_c2, const float* __restrict__ b_c2,
    const float* __restrict__ W_p2, const float* __restrict__ b_p2,
    const float* __restrict__ W_c3, const float* __restrict__ b_c3,
    const float* __restrict__ rot, const float* __restrict__ ent,
    float* __restrict__ l_arr, float4* __restrict__ o_arr) {
  __shared__ float4 kv[2 * CHUNK];  // interleaved {k4, v4}: 8 KB

  const int t = threadIdx.x;
  const int qi = blockIdx.x * BLK + t;    // query row this thread owns
  const int ki = blockIdx.y * CHUNK + t;  // key row this thread produces

  const float4* in4 = (const float4*)in;
  float4 A0 = in4[2 * qi + 0], A1 = in4[2 * qi + 1];
  float4 B0 = in4[2 * ki + 0], B1 = in4[2 * ki + 1];

  float xq[16], tq[16], xk[16], tk[16];
  xq[0] = A0.x; xq[1] = A0.y; xq[2] = A0.z; xq[3] = A0.w;
  xq[4] = A1.x; xq[5] = A1.y; xq[6] = A1.z; xq[7] = A1.w;
  xk[0] = B0.x; xk[1] = B0.y; xk[2] = B0.z; xk[3] = B0.w;
  xk[4] = B1.x; xk[5] = B1.y; xk[6] = B1.z; xk[7] = B1.w;

  layer2_tanh<8, 16>(xq, xk, tq, tk, W_fm, b_fm);
  layer2_tanh<16, 16>(tq, tk, xq, xk, W_c1, b_c1);
  layer2_tanh<16, 12>(xq, xk, tq, tk, W_p1, b_p1);
  layer2_tanh<12, 8>(tq, tk, xq, xk, W_c2, b_c2);
  layer2_tanh<8, 4>(xq, xk, tq, tk, W_p2, b_p2);
  layer2_tanh<4, 4>(tq, tk, xq, xk, W_c3, b_c3);
  // final x_q in xq[0..3], x_k in xk[0..3]

  float qd[4], kd[4];
#pragma unroll
  for (int d = 0; d < 4; d++) {
    qd[d] = xq[0] * rot[0 * 4 + d] + xq[1] * rot[1 * 4 + d] +
            xq[2] * rot[2 * 4 + d] + xq[3] * rot[3 * 4 + d];
    kd[d] = xk[0] * ent[0 * 4 + d] + xk[1] * ent[1 * 4 + d] +
            xk[2] * ent[2 * 4 + d] + xk[3] * ent[3 * 4 + d];
  }

  kv[2 * t + 0] = make_float4(kd[0], kd[1], kd[2], kd[3]);
  kv[2 * t + 1] = make_float4(xk[0], xk[1], xk[2], xk[3]);
  __syncthreads();

  // softmax scale 1/sqrt(4) folded into q (same as verified kernel)
  const float4 Q =
      make_float4(qd[0] * 0.5f, qd[1] * 0.5f, qd[2] * 0.5f, qd[3] * 0.5f);

  float l0 = 0.f, l1 = 0.f;
  float4 o0 = make_float4(0.f, 0.f, 0.f, 0.f);
  float4 o1 = make_float4(0.f, 0.f, 0.f, 0.f);
#pragma unroll 4
  for (int j = 0; j < CHUNK; j += 2) {
    // uniform LDS address across the wave -> broadcast, conflict-free
    const float4 ka = kv[2 * j + 0];
    const float4 va = kv[2 * j + 1];
    const float4 kb = kv[2 * j + 2];
    const float4 vb = kv[2 * j + 3];
    float s0 = dot4(Q, ka);
    float s1 = dot4(Q, kb);
    float p0 = __expf(s0);
    float p1 = __expf(s1);
    l0 += p0;
    l1 += p1;
    o0.x = fmaf(p0, va.x, o0.x); o0.y = fmaf(p0, va.y, o0.y);
    o0.z = fmaf(p0, va.z, o0.z); o0.w = fmaf(p0, va.w, o0.w);
    o1.x = fmaf(p1, vb.x, o1.x); o1.y = fmaf(p1, vb.y, o1.y);
    o1.z = fmaf(p1, vb.z, o1.z); o1.w = fmaf(p1, vb.w, o1.w);
  }
  const int idx = blockIdx.y * BATCH + qi;
  l_arr[idx] = l0 + l1;
  o_arr[idx] = make_float4(o0.x + o1.x, o0.y + o1.y, o0.z + o1.z, o0.w + o1.w);
}

__global__ __launch_bounds__(BLK) void combine_kernel(
    const float* __restrict__ l_arr, const float4* __restrict__ o_arr,
    const float* __restrict__ conv_w, const float* __restrict__ conv_b,
    const float* __restrict__ head_w, const float* __restrict__ head_b,
    float* __restrict__ out) {
  const int qi = blockIdx.x * BLK + threadIdx.x;
  float l = 0.f;
  float4 o = make_float4(0.f, 0.f, 0.f, 0.f);
#pragma unroll
  for (int s = 0; s < NSPLIT; s++) {
    l += l_arr[s * BATCH + qi];
    float4 os = o_arr[s * BATCH + qi];
    o.x += os.x; o.y += os.y; o.z += os.z; o.w += os.w;
  }
  const float inv = 1.0f / l;
  float z = o.x * inv * conv_w[0] + o.y * inv * conv_w[1] +
            o.z * inv * conv_w[2] + o.w * inv * conv_w[3] + conv_b[0];
  float filtered = 1.0f / (1.0f + __expf(-z));
  float logit = fmaf(filtered, head_w[0], head_b[0]);
  out[qi] = 1.0f / (1.0f + __expf(-logit));
}

extern "C" void kernel_launch(void* const* d_in, const int* in_sizes, int n_in,
                              void* d_out, int out_size, void* d_ws,
                              size_t ws_size, hipStream_t stream) {
  const float* in   = (const float*)d_in[0];
  const float* W_fm = (const float*)d_in[1];
  const float* b_fm = (const float*)d_in[2];
  const float* W_c1 = (const float*)d_in[3];
  const float* b_c1 = (const float*)d_in[4];
  const float* W_p1 = (const float*)d_in[5];
  const float* b_p1 = (const float*)d_in[6];
  const float* W_c2 = (const float*)d_in[7];
  const float* b_c2 = (const float*)d_in[8];
  const float* W_p2 = (const float*)d_in[9];
  const float* b_p2 = (const float*)d_in[10];
  const float* W_c3 = (const float*)d_in[11];
  const float* b_c3 = (const float*)d_in[12];
  const float* rot  = (const float*)d_in[13];
  const float* ent  = (const float*)d_in[14];
  const float* conv_w = (const float*)d_in[15];
  const float* conv_b = (const float*)d_in[16];
  const float* head_w = (const float*)d_in[17];
  const float* head_b = (const float*)d_in[18];
  float* out = (float*)d_out;

  char* ws = (char*)d_ws;
  float*  l_arr = (float*)ws;                                    // 1 MB
  float4* o_arr = (float4*)(ws + (size_t)NSPLIT * BATCH * 4);    // 4 MB

  dim3 grid(BATCH / BLK, NSPLIT);
  fused_attn<<<grid, BLK, 0, stream>>>(
      in, W_fm, b_fm, W_c1, b_c1, W_p1, b_p1, W_c2, b_c2, W_p2, b_p2, W_c3,
      b_c3, rot, ent, l_arr, o_arr);

  combine_kernel<<<BATCH / BLK, BLK, 0, stream>>>(
      l_arr, o_arr, conv_w, conv_b, head_w, head_b, out);
}

// Round 2
// 127.102 us; speedup vs baseline: 1.0226x; 1.0226x over previous
//
#include <hip/hip_runtime.h>
#include <math.h>

#define BATCH 8192
#define BLK 256
#define NSPLIT 32
#define CHUNK (BATCH / NSPLIT)  // 256 keys per split

// Raw v_exp_f32 (2^x). Guarded: fallback keeps exact exp semantics.
#if __has_builtin(__builtin_amdgcn_exp2f)
#define EXP2F(x) __builtin_amdgcn_exp2f(x)
#else
#define EXP2F(x) __expf((x)*0.69314718055994530942f)
#endif

// Branch-free fast tanh: tanh(x) = 1 - 2/(e^{2x}+1), e^{2x} = 2^(x*2*log2 e).
// mul+exp+add+rcp+fma = 5 instr, saturates exactly at +-inf. Verified absmax
// 0.0 vs reference in round 1.
__device__ __forceinline__ float tanh_fast(float x) {
  float e = EXP2F(x * 2.88539008177792681472f);  // 2*log2(e)
  return fmaf(-2.0f, __builtin_amdgcn_rcpf(e + 1.0f), 1.0f);
}

// Single-row Linear+tanh. Weight/bias addresses are wave-uniform -> compiler
// emits s_load on the scalar pipe (scalar L1 resident, zero VALU cost).
// The OUT independent accumulators provide the ILP; fully unrolled ->
// registers only.
template <int IN, int OUT>
__device__ __forceinline__ void layer_tanh(const float* x, float* y,
                                           const float* __restrict__ W,
                                           const float* __restrict__ bias) {
  float acc[OUT];
#pragma unroll
  for (int o = 0; o < OUT; o++) acc[o] = bias[o];
#pragma unroll
  for (int i = 0; i < IN; i++) {
    float xi = x[i];
#pragma unroll
    for (int o = 0; o < OUT; o++) acc[o] = fmaf(xi, W[i * OUT + o], acc[o]);
  }
#pragma unroll
  for (int o = 0; o < OUT; o++) y[o] = tanh_fast(acc[o]);
}

// Deduplicated MLP: one eval per row (the fused round-1 kernel paid this 64x).
// Produces qv[r] = (x @ rot) * 0.5 * log2(e)  (softmax scale + exp2 fold) and
// interleaved kvx[2r] = x @ ent, kvx[2r+1] = x.
__global__ __launch_bounds__(BLK) void mlp_kernel(
    const float* __restrict__ in,
    const float* __restrict__ W_fm, const float* __restrict__ b_fm,
    const float* __restrict__ W_c1, const float* __restrict__ b_c1,
    const float* __restrict__ W_p1, const float* __restrict__ b_p1,
    const float* __restrict__ W_c2, const float* __restrict__ b_c2,
    const float* __restrict__ W_p2, const float* __restrict__ b_p2,
    const float* __restrict__ W_c3, const float* __restrict__ b_c3,
    const float* __restrict__ rot, const float* __restrict__ ent,
    float4* __restrict__ qv, float4* __restrict__ kvx) {
  const int r = blockIdx.x * BLK + threadIdx.x;
  const float4* in4 = (const float4*)in;
  float4 i0 = in4[2 * r + 0], i1 = in4[2 * r + 1];
  float a[16], b[16];
  a[0] = i0.x; a[1] = i0.y; a[2] = i0.z; a[3] = i0.w;
  a[4] = i1.x; a[5] = i1.y; a[6] = i1.z; a[7] = i1.w;

  layer_tanh<8, 16>(a, b, W_fm, b_fm);
  layer_tanh<16, 16>(b, a, W_c1, b_c1);
  layer_tanh<16, 12>(a, b, W_p1, b_p1);
  layer_tanh<12, 8>(b, a, W_c2, b_c2);
  layer_tanh<8, 4>(a, b, W_p2, b_p2);
  layer_tanh<4, 4>(b, a, W_c3, b_c3);
  // final x in a[0..3]
  float q[4], k[4];
#pragma unroll
  for (int d = 0; d < 4; d++) {
    q[d] = a[0] * rot[0 * 4 + d] + a[1] * rot[1 * 4 + d] +
           a[2] * rot[2 * 4 + d] + a[3] * rot[3 * 4 + d];
    k[d] = a[0] * ent[0 * 4 + d] + a[1] * ent[1 * 4 + d] +
           a[2] * ent[2 * 4 + d] + a[3] * ent[3 * 4 + d];
  }
  const float qs = 0.72134752044448170368f;  // 0.5 (softmax) * log2(e) (exp2)
  qv[r] = make_float4(q[0] * qs, q[1] * qs, q[2] * qs, q[3] * qs);
  kvx[2 * r + 0] = make_float4(k[0], k[1], k[2], k[3]);
  kvx[2 * r + 1] = make_float4(a[0], a[1], a[2], a[3]);
}

__device__ __forceinline__ float dot4(float4 a, float4 b) {
  return fmaf(a.x, b.x, fmaf(a.y, b.y, fmaf(a.z, b.z, a.w * b.w)));
}

// No-max single-pass split attention (|s| << 88 so exp2 cannot overflow; the
// max-rescale cancels exactly in o/l). K/V addresses depend only on
// blockIdx.y and the loop counter -> wave-uniform -> scalar-pipe s_load:
// zero LDS, zero vector-memory in the hot loop. 4 independent
// accumulator streams pipeline the quarter-rate exp chain.
__global__ __launch_bounds__(BLK) void attn_partial(
    const float4* __restrict__ kvx, const float4* __restrict__ qv,
    float* __restrict__ l_arr, float4* __restrict__ o_arr) {
  const int t = threadIdx.x;
  const int qi = blockIdx.x * BLK + t;
  const int c0 = blockIdx.y * CHUNK;
  const float4 q = qv[qi];

  float l0 = 0.f, l1 = 0.f, l2 = 0.f, l3 = 0.f;
  float4 o0 = make_float4(0.f, 0.f, 0.f, 0.f);
  float4 o1 = make_float4(0.f, 0.f, 0.f, 0.f);
  float4 o2 = make_float4(0.f, 0.f, 0.f, 0.f);
  float4 o3 = make_float4(0.f, 0.f, 0.f, 0.f);
#pragma unroll 2
  for (int j = 0; j < CHUNK; j += 4) {
    const int base = (c0 + j) * 2;
    const float4 ka = kvx[base + 0];
    const float4 va = kvx[base + 1];
    const float4 kb = kvx[base + 2];
    const float4 vb = kvx[base + 3];
    const float4 kc = kvx[base + 4];
    const float4 vc = kvx[base + 5];
    const float4 kd = kvx[base + 6];
    const float4 vd = kvx[base + 7];
    float p0 = EXP2F(dot4(q, ka));
    float p1 = EXP2F(dot4(q, kb));
    float p2 = EXP2F(dot4(q, kc));
    float p3 = EXP2F(dot4(q, kd));
    l0 += p0; l1 += p1; l2 += p2; l3 += p3;
    o0.x = fmaf(p0, va.x, o0.x); o0.y = fmaf(p0, va.y, o0.y);
    o0.z = fmaf(p0, va.z, o0.z); o0.w = fmaf(p0, va.w, o0.w);
    o1.x = fmaf(p1, vb.x, o1.x); o1.y = fmaf(p1, vb.y, o1.y);
    o1.z = fmaf(p1, vb.z, o1.z); o1.w = fmaf(p1, vb.w, o1.w);
    o2.x = fmaf(p2, vc.x, o2.x); o2.y = fmaf(p2, vc.y, o2.y);
    o2.z = fmaf(p2, vc.z, o2.z); o2.w = fmaf(p2, vc.w, o2.w);
    o3.x = fmaf(p3, vd.x, o3.x); o3.y = fmaf(p3, vd.y, o3.y);
    o3.z = fmaf(p3, vd.z, o3.z); o3.w = fmaf(p3, vd.w, o3.w);
  }
  const int idx = blockIdx.y * BATCH + qi;
  l_arr[idx] = (l0 + l1) + (l2 + l3);
  o_arr[idx] = make_float4((o0.x + o1.x) + (o2.x + o3.x),
                           (o0.y + o1.y) + (o2.y + o3.y),
                           (o0.z + o1.z) + (o2.z + o3.z),
                           (o0.w + o1.w) + (o2.w + o3.w));
}

__global__ __launch_bounds__(BLK) void combine_kernel(
    const float* __restrict__ l_arr, const float4* __restrict__ o_arr,
    const float* __restrict__ conv_w, const float* __restrict__ conv_b,
    const float* __restrict__ head_w, const float* __restrict__ head_b,
    float* __restrict__ out) {
  const int qi = blockIdx.x * BLK + threadIdx.x;
  float l = 0.f;
  float4 o = make_float4(0.f, 0.f, 0.f, 0.f);
#pragma unroll
  for (int s = 0; s < NSPLIT; s++) {
    l += l_arr[s * BATCH + qi];
    float4 os = o_arr[s * BATCH + qi];
    o.x += os.x; o.y += os.y; o.z += os.z; o.w += os.w;
  }
  const float inv = 1.0f / l;
  float z = o.x * inv * conv_w[0] + o.y * inv * conv_w[1] +
            o.z * inv * conv_w[2] + o.w * inv * conv_w[3] + conv_b[0];
  float filtered = 1.0f / (1.0f + __expf(-z));
  float logit = fmaf(filtered, head_w[0], head_b[0]);
  out[qi] = 1.0f / (1.0f + __expf(-logit));
}

extern "C" void kernel_launch(void* const* d_in, const int* in_sizes, int n_in,
                              void* d_out, int out_size, void* d_ws,
                              size_t ws_size, hipStream_t stream) {
  const float* in   = (const float*)d_in[0];
  const float* W_fm = (const float*)d_in[1];
  const float* b_fm = (const float*)d_in[2];
  const float* W_c1 = (const float*)d_in[3];
  const float* b_c1 = (const float*)d_in[4];
  const float* W_p1 = (const float*)d_in[5];
  const float* b_p1 = (const float*)d_in[6];
  const float* W_c2 = (const float*)d_in[7];
  const float* b_c2 = (const float*)d_in[8];
  const float* W_p2 = (const float*)d_in[9];
  const float* b_p2 = (const float*)d_in[10];
  const float* W_c3 = (const float*)d_in[11];
  const float* b_c3 = (const float*)d_in[12];
  const float* rot  = (const float*)d_in[13];
  const float* ent  = (const float*)d_in[14];
  const float* conv_w = (const float*)d_in[15];
  const float* conv_b = (const float*)d_in[16];
  const float* head_w = (const float*)d_in[17];
  const float* head_b = (const float*)d_in[18];
  float* out = (float*)d_out;

  char* ws = (char*)d_ws;
  float4* qv  = (float4*)(ws + 0);                 // 128 KB
  float4* kvx = (float4*)(ws + (128 << 10));       // 256 KB (k/v interleaved)
  float*  l_arr = (float*)(ws + (384 << 10));      // NSPLIT*BATCH*4 = 1 MB
  float4* o_arr = (float4*)(ws + (384 << 10) + NSPLIT * BATCH * 4);  // 4 MB

  mlp_kernel<<<BATCH / BLK, BLK, 0, stream>>>(
      in, W_fm, b_fm, W_c1, b_c1, W_p1, b_p1, W_c2, b_c2, W_p2, b_p2, W_c3,
      b_c3, rot, ent, qv, kvx);

  dim3 grid(BATCH / BLK, NSPLIT);
  attn_partial<<<grid, BLK, 0, stream>>>(kvx, qv, l_arr, o_arr);

  combine_kernel<<<BATCH / BLK, BLK, 0, stream>>>(
      l_arr, o_arr, conv_w, conv_b, head_w, head_b, out);
}